// Round 6
// baseline (216.079 us; speedup 1.0000x reference)
//
#include <hip/hip_runtime.h>
#include <hip/hip_fp16.h>
#include <math.h>

// N=100000 nodes, E=6400000 edges, avg degree 64.
// out[n] = [cos(th_n), sin(th_n), w_n],  w_n = S_y / max(||S||, eps),
//   S_x = cos(th)*C + sin(th)*S,  S_y = cos(th)*S - sin(th)*C,
//   C_n = sum_{e:dst=n} cos(x[src_e]),  S_n = sum_{e:dst=n} sin(x[src_e]).
//
// History: R1 global atomics 634us. R2 LDS rescan 200us (latency chains).
// R3 unconditional atomics 2ms REGRESSION. R4 pipelined rescan 199us
// (L3-BW-bound, 16x rescan). R5 index counting-sort 196us: phase2 72us was
// latency-starved (bucket load -> cst gather -> atomic chain at 11 waves/CU),
// phase1 ~90us (edges read twice + cursor atomics).
// R6: value-packed sort. Phase1 reads edges ONCE (entries held in VGPRs
// across the reserve barrier), gathers L2-resident cst[src], writes 8B
// entries {fp16x2(cos,sin), (p<<16)|dst_local}. Phase2 is a pure coalesced
// stream -> cvt -> 2 LDS atomics, NPART=128 (6.3KB LDS) -> 32 waves/CU.

#define EPS 1e-12f

// ---- R6 packed-sort params ----
#define NP2   128
#define RMAX2 1024       // 2*RMAX2 floats = 8KB LDS in phase2
#define BLK1  256
#define EPT   16
#define CH    (BLK1 * EPT)   // 4096 edges per phase-1 block
#define BLK2  256

// ---- R5 fallback params ----
#define NPART 16
#define RMAX  6250
#define BLK5  512
#define CH5   8192

static __device__ __forceinline__ unsigned h2_to_u(__half2 h) {
    union { __half2 h; unsigned u; } c; c.h = h; return c.u;
}
static __device__ __forceinline__ __half2 u_to_h2(unsigned u) {
    union { __half2 h; unsigned u; } c; c.u = u; return c.h;
}

// ---------------- common: cos/sin table + gcount zero ----------------

__global__ void build_cs_kernel(const float* __restrict__ x,
                                float2* __restrict__ cst,
                                int* __restrict__ gcount, int N, int npart) {
    int i = blockIdx.x * blockDim.x + threadIdx.x;
    if (blockIdx.x == 0 && threadIdx.x < npart) gcount[threadIdx.x] = 0;
    if (i < N) {
        float sn, cs;
        __sincosf(x[i], &sn, &cs);
        cst[i] = make_float2(cs, sn);
    }
}

// ---------------- R6 phase 1: single-read pack & bucket ----------------

__global__ __launch_bounds__(BLK1) void p1_pack_kernel(
        const int* __restrict__ esrc,
        const int* __restrict__ edst,
        const float2* __restrict__ cst,
        uint2* __restrict__ bucket,     // NP2 regions of cap entries
        int* __restrict__ gcount,
        int E, int R, unsigned inv32, int cap) {
    __shared__ int hist[NP2];
    __shared__ int cursor[NP2];
    for (int k = threadIdx.x; k < NP2; k += BLK1) hist[k] = 0;
    __syncthreads();

    const int beg = blockIdx.x * CH;
    const bool fast = (beg + CH <= E);
    uint2 ent[EPT];

    if (fast) {
        int4 d4[4], s4[4];
        #pragma unroll
        for (int g = 0; g < 4; ++g) {
            const int i = beg + g * (BLK1 * 4) + threadIdx.x * 4;
            d4[g] = *(const int4*)&edst[i];
            s4[g] = *(const int4*)&esrc[i];
        }
        #pragma unroll
        for (int g = 0; g < 4; ++g) {
            const int dd[4] = {d4[g].x, d4[g].y, d4[g].z, d4[g].w};
            const int ss[4] = {s4[g].x, s4[g].y, s4[g].z, s4[g].w};
            #pragma unroll
            for (int j = 0; j < 4; ++j) {
                const unsigned p = __umulhi((unsigned)dd[j], inv32);
                const unsigned l = (unsigned)dd[j] - p * (unsigned)R;
                atomicAdd(&hist[p], 1);
                const float2 v = cst[ss[j]];
                ent[g * 4 + j].x = h2_to_u(__floats2half2_rn(v.x, v.y));
                ent[g * 4 + j].y = (p << 16) | l;
            }
        }
    } else {
        for (int i = beg + threadIdx.x; i < E; i += BLK1)
            atomicAdd(&hist[__umulhi((unsigned)edst[i], inv32)], 1);
    }
    __syncthreads();

    if (threadIdx.x < NP2) {
        int base = atomicAdd(&gcount[threadIdx.x], hist[threadIdx.x]);
        cursor[threadIdx.x] = threadIdx.x * cap + base;
    }
    __syncthreads();

    if (fast) {
        #pragma unroll
        for (int k = 0; k < EPT; ++k) {
            const unsigned p = ent[k].y >> 16;
            const int slot = atomicAdd(&cursor[p], 1);
            if (slot < (int)(p + 1) * cap) bucket[slot] = ent[k];
        }
    } else {
        for (int i = beg + threadIdx.x; i < E; i += BLK1) {
            const unsigned d = (unsigned)edst[i];
            const unsigned p = __umulhi(d, inv32);
            const unsigned l = d - p * (unsigned)R;
            const float2 v = cst[esrc[i]];
            uint2 e;
            e.x = h2_to_u(__floats2half2_rn(v.x, v.y));
            e.y = (p << 16) | l;
            const int slot = atomicAdd(&cursor[p], 1);
            if (slot < (int)(p + 1) * cap) bucket[slot] = e;
        }
    }
}

// ---------------- R6 phase 2: pure stream + LDS accumulate ----------------

__global__ __launch_bounds__(BLK2) void p2_accum_kernel(
        const uint2* __restrict__ bucket,
        const int* __restrict__ gcount,
        float* __restrict__ partials,   // [NP2*SL][2*R]
        int R, int cap, int SL) {
    __shared__ float lacc[2 * RMAX2];
    const int p = blockIdx.x / SL;
    const int s = blockIdx.x % SL;

    for (int k = threadIdx.x; k < 2 * R; k += BLK2) lacc[k] = 0.0f;
    __syncthreads();

    const int cnt = min(gcount[p], cap);
    const int per = (((cnt + SL - 1) / SL) + 3) & ~3;
    const int beg = s * per;
    const int end = min(beg + per, cnt);
    const int end4 = beg + (max(end - beg, 0) & ~3);
    const uint2* bk = bucket + (size_t)p * cap;
    const uint4* b4 = (const uint4*)bk;

    for (int i = beg + threadIdx.x * 4; i < end4; i += BLK2 * 4) {
        const uint4 a = b4[i >> 1];
        const uint4 b = b4[(i >> 1) + 1];
        const float2 v0 = __half22float2(u_to_h2(a.x));
        const float2 v1 = __half22float2(u_to_h2(a.z));
        const float2 v2 = __half22float2(u_to_h2(b.x));
        const float2 v3 = __half22float2(u_to_h2(b.z));
        const unsigned l0 = a.y & 0xffffu, l1 = a.w & 0xffffu;
        const unsigned l2 = b.y & 0xffffu, l3 = b.w & 0xffffu;
        atomicAdd(&lacc[l0], v0.x); atomicAdd(&lacc[l0 + R], v0.y);
        atomicAdd(&lacc[l1], v1.x); atomicAdd(&lacc[l1 + R], v1.y);
        atomicAdd(&lacc[l2], v2.x); atomicAdd(&lacc[l2 + R], v2.y);
        atomicAdd(&lacc[l3], v3.x); atomicAdd(&lacc[l3 + R], v3.y);
    }
    for (int i = end4 + threadIdx.x; i < end; i += BLK2) {
        const uint2 e = bk[i];
        const float2 v = __half22float2(u_to_h2(e.x));
        const unsigned l = e.y & 0xffffu;
        atomicAdd(&lacc[l], v.x); atomicAdd(&lacc[l + R], v.y);
    }

    __syncthreads();
    float* dst = partials + (size_t)blockIdx.x * (2 * R);
    for (int k = threadIdx.x; k < 2 * R; k += BLK2) dst[k] = lacc[k];
}

// ---------------- shared reduce + epilogue ----------------

__global__ void reduce_node_kernel(const float* __restrict__ theta,
                                   const float* __restrict__ buf,
                                   float* __restrict__ out, int N, int R,
                                   int nslice) {
    int n = blockIdx.x * blockDim.x + threadIdx.x;
    if (n >= N) return;
    int p = n / R, j = n - p * R;
    float C = 0.0f, Sv = 0.0f;
    size_t base = (size_t)p * nslice * 2 * R + j;
    #pragma unroll 8
    for (int s = 0; s < nslice; ++s) {
        const float* b = buf + base + (size_t)s * 2 * R;
        C  += b[0];
        Sv += b[R];
    }
    float sn, cs;
    __sincosf(theta[n], &sn, &cs);
    float nrm = fmaxf(sqrtf(C * C + Sv * Sv), EPS);
    out[3 * n + 0] = cs;
    out[3 * n + 1] = sn;
    out[3 * n + 2] = (cs * Sv - sn * C) / nrm;
}

// ---------------- R5 fallback: index counting sort ----------------

__global__ __launch_bounds__(BLK1) void phase1_bucket_kernel(
        const int* __restrict__ esrc,
        const int* __restrict__ edst,
        unsigned* __restrict__ bucket,
        int* __restrict__ gcount,
        int E, int R, unsigned inv32, int cap) {
    __shared__ int hist[NPART];
    __shared__ int cursor[NPART];
    if (threadIdx.x < NPART) hist[threadIdx.x] = 0;
    __syncthreads();
    const int beg = blockIdx.x * CH5;
    const int end = min(beg + CH5, E);
    const int end4 = beg + (max(end - beg, 0) & ~3);
    for (int i = beg + threadIdx.x * 4; i < end4; i += BLK1 * 4) {
        const int4 d4 = *(const int4*)&edst[i];
        atomicAdd(&hist[__umulhi((unsigned)d4.x, inv32)], 1);
        atomicAdd(&hist[__umulhi((unsigned)d4.y, inv32)], 1);
        atomicAdd(&hist[__umulhi((unsigned)d4.z, inv32)], 1);
        atomicAdd(&hist[__umulhi((unsigned)d4.w, inv32)], 1);
    }
    for (int i = end4 + threadIdx.x; i < end; i += BLK1)
        atomicAdd(&hist[__umulhi((unsigned)edst[i], inv32)], 1);
    __syncthreads();
    if (threadIdx.x < NPART) {
        int base = atomicAdd(&gcount[threadIdx.x], hist[threadIdx.x]);
        cursor[threadIdx.x] = threadIdx.x * cap + base;
    }
    __syncthreads();
    for (int i = beg + threadIdx.x; i < end; i += BLK1) {
        int d = edst[i];
        unsigned p = __umulhi((unsigned)d, inv32);
        unsigned l = (unsigned)d - p * R;
        int slot = atomicAdd(&cursor[p], 1);
        if (slot < (int)(p + 1) * cap) bucket[slot] = ((unsigned)esrc[i] << 13) | l;
    }
}

__global__ __launch_bounds__(BLK5) void phase2_accum_kernel(
        const unsigned* __restrict__ bucket,
        const float2* __restrict__ cst,
        const int* __restrict__ gcount,
        float* __restrict__ partials,
        int R, int cap, int SL) {
    __shared__ float lacc[2 * RMAX];
    const int p = blockIdx.x / SL;
    const int s = blockIdx.x % SL;
    for (int k = threadIdx.x; k < 2 * R; k += BLK5) lacc[k] = 0.0f;
    __syncthreads();
    const int cnt = min(gcount[p], cap);
    const int per = (((cnt + SL - 1) / SL) + 3) & ~3;
    const unsigned* bk = bucket + (size_t)p * cap;
    const int beg = s * per;
    const int end = min(beg + per, cnt);
    const int end4 = beg + (max(end - beg, 0) & ~3);
    for (int i = beg + threadIdx.x * 4; i < end4; i += BLK5 * 4) {
        const uint4 e4 = *(const uint4*)&bk[i];
        const unsigned l0 = e4.x & 8191u, l1 = e4.y & 8191u;
        const unsigned l2 = e4.z & 8191u, l3 = e4.w & 8191u;
        const float2 v0 = cst[e4.x >> 13];
        const float2 v1 = cst[e4.y >> 13];
        const float2 v2 = cst[e4.z >> 13];
        const float2 v3 = cst[e4.w >> 13];
        atomicAdd(&lacc[l0], v0.x); atomicAdd(&lacc[l0 + R], v0.y);
        atomicAdd(&lacc[l1], v1.x); atomicAdd(&lacc[l1 + R], v1.y);
        atomicAdd(&lacc[l2], v2.x); atomicAdd(&lacc[l2 + R], v2.y);
        atomicAdd(&lacc[l3], v3.x); atomicAdd(&lacc[l3 + R], v3.y);
    }
    for (int i = end4 + threadIdx.x; i < end; i += BLK5) {
        const unsigned e = bk[i];
        const unsigned l = e & 8191u;
        const float2 v = cst[e >> 13];
        atomicAdd(&lacc[l], v.x); atomicAdd(&lacc[l + R], v.y);
    }
    __syncthreads();
    float* dst = partials + (size_t)blockIdx.x * (2 * R);
    for (int k = threadIdx.x; k < 2 * R; k += BLK5) dst[k] = lacc[k];
}

// ---------------- R1 fallback: global atomics ----------------

__global__ void zero_kernel(float* __restrict__ p, int n) {
    int i = blockIdx.x * blockDim.x + threadIdx.x;
    if (i < n) p[i] = 0.0f;
}

__global__ void edge_atomic_kernel(const float* __restrict__ x,
                                   const float* __restrict__ theta,
                                   const int* __restrict__ esrc,
                                   const int* __restrict__ edst,
                                   float* __restrict__ acc, int E) {
    int i = blockIdx.x * blockDim.x + threadIdx.x;
    if (i >= E) return;
    int s = esrc[i], d = edst[i];
    float dt = x[s] - theta[d];
    float sn, cs;
    __sincosf(dt, &sn, &cs);
    atomicAdd(&acc[2 * d], cs);
    atomicAdd(&acc[2 * d + 1], sn);
}

__global__ void node_atomic_kernel(const float* __restrict__ theta,
                                   const float* __restrict__ acc,
                                   float* __restrict__ out, int N) {
    int n = blockIdx.x * blockDim.x + threadIdx.x;
    if (n >= N) return;
    float sn, cs;
    __sincosf(theta[n], &sn, &cs);
    float sx = acc[2 * n], sy = acc[2 * n + 1];
    float nrm = fmaxf(sqrtf(sx * sx + sy * sy), EPS);
    out[3 * n + 0] = cs;
    out[3 * n + 1] = sn;
    out[3 * n + 2] = sy / nrm;
}

// ---------------- launch ----------------

static bool magic_u32(int R, int N, unsigned& inv_out) {
    unsigned long long inv64 = (0x100000000ULL + (unsigned)R - 1) / (unsigned)R;
    if (inv64 >= 0x100000000ULL) return false;
    unsigned long long merr = inv64 * (unsigned)R - 0x100000000ULL;
    if (merr * (unsigned long long)(N > 0 ? N - 1 : 0) >= 0x100000000ULL) return false;
    inv_out = (unsigned)inv64;
    return true;
}

extern "C" void kernel_launch(void* const* d_in, const int* in_sizes, int n_in,
                              void* d_out, int out_size, void* d_ws, size_t ws_size,
                              hipStream_t stream) {
    const float* x     = (const float*)d_in[0];
    const float* theta = (const float*)d_in[1];
    const int*   esrc  = (const int*)d_in[2];
    const int*   edst  = (const int*)d_in[3];
    float*       out   = (float*)d_out;

    const int N = in_sizes[0];
    const int E = in_sizes[2];
    const size_t cst_bytes = (size_t)N * sizeof(float2);

    // ---------- R6 packed-value path ----------
    {
        const int R2 = (N + NP2 - 1) / NP2;
        unsigned inv32;
        const bool ok = (R2 <= RMAX2) && (R2 < 65536) && magic_u32(R2, N, inv32);
        if (ok) {
            const int cap = (((E + NP2 - 1) / NP2) + 4096 + 3) & ~3;  // ~18 sigma slack
            const size_t bucket_bytes = (size_t)NP2 * cap * sizeof(uint2);
            int SL = 0;
            for (int cand : {16, 8, 4}) {
                size_t need = bucket_bytes + (size_t)NP2 * cand * 2 * R2 * sizeof(float)
                              + cst_bytes + 1024;
                if (ws_size >= need) { SL = cand; break; }
            }
            if (SL > 0) {
                const size_t partial_bytes = (size_t)NP2 * SL * 2 * R2 * sizeof(float);
                uint2*  bucket   = (uint2*)d_ws;
                float*  partials = (float*)((char*)d_ws + bucket_bytes);
                float2* cst      = (float2*)((char*)d_ws + bucket_bytes + partial_bytes);
                int*    gcount   = (int*)((char*)d_ws + bucket_bytes + partial_bytes + cst_bytes);

                build_cs_kernel<<<(N + 255) / 256, 256, 0, stream>>>(x, cst, gcount, N, NP2);
                p1_pack_kernel<<<(E + CH - 1) / CH, BLK1, 0, stream>>>(
                    esrc, edst, cst, bucket, gcount, E, R2, inv32, cap);
                p2_accum_kernel<<<NP2 * SL, BLK2, 0, stream>>>(
                    bucket, gcount, partials, R2, cap, SL);
                reduce_node_kernel<<<(N + 255) / 256, 256, 0, stream>>>(
                    theta, partials, out, N, R2, SL);
                return;
            }
        }
    }

    // ---------- R5 index-sort fallback ----------
    {
        const int R = (N + NPART - 1) / NPART;
        unsigned inv32;
        const bool pack_ok = (R <= 8191) && ((long long)N <= (1LL << 17)) &&
                             (R <= RMAX) && magic_u32(R, N, inv32);
        const int cap = (((E + NPART - 1) / NPART) + 8192 + 3) & ~3;
        const size_t bucket_bytes = (size_t)NPART * cap * sizeof(unsigned);
        int SL = 0;
        for (int cand : {32, 16, 8}) {
            size_t need = bucket_bytes + (size_t)NPART * cand * 2 * R * sizeof(float)
                          + cst_bytes + 1024;
            if (ws_size >= need) { SL = cand; break; }
        }
        if (pack_ok && SL > 0) {
            const size_t partial_bytes = (size_t)NPART * SL * 2 * R * sizeof(float);
            unsigned* bucket   = (unsigned*)d_ws;
            float*    partials = (float*)((char*)d_ws + bucket_bytes);
            float2*   cst      = (float2*)((char*)d_ws + bucket_bytes + partial_bytes);
            int*      gcount   = (int*)((char*)d_ws + bucket_bytes + partial_bytes + cst_bytes);

            build_cs_kernel<<<(N + 255) / 256, 256, 0, stream>>>(x, cst, gcount, N, NPART);
            phase1_bucket_kernel<<<(E + CH5 - 1) / CH5, BLK1, 0, stream>>>(
                esrc, edst, bucket, gcount, E, R, inv32, cap);
            phase2_accum_kernel<<<NPART * SL, BLK5, 0, stream>>>(
                bucket, cst, gcount, partials, R, cap, SL);
            reduce_node_kernel<<<(N + 255) / 256, 256, 0, stream>>>(
                theta, partials, out, N, R, SL);
            return;
        }
    }

    // ---------- R1 global-atomic fallback ----------
    {
        float* acc = (float*)d_ws;
        const int B = 256;
        zero_kernel<<<(2 * N + B - 1) / B, B, 0, stream>>>(acc, 2 * N);
        edge_atomic_kernel<<<(E + B - 1) / B, B, 0, stream>>>(x, theta, esrc, edst, acc, E);
        node_atomic_kernel<<<(N + B - 1) / B, B, 0, stream>>>(theta, acc, out, N);
    }
}